// Round 7
// baseline (902.277 us; speedup 1.0000x reference)
//
#include <hip/hip_runtime.h>
#include <hip/hip_bf16.h>
#include <math.h>

#define N_NODES 40000
#define NE      640000
#define FIN     33
#define H       128
#define COUT    3
#define NLAYERS 8
#define ALPHA   0.1f
#define THETA   0.5f
#define CAP     96             // max bucket capacity; deg ~ Poisson(16), P(>96) ~ 1e-40
#define HEADROOM 16.0f         // fp8 scale headroom: covers <16x single-layer growth

// setup mega-kernel block ranges (scatter FIRST — longest per-block branch)
#define SB_SCAT 625            // scatter: 625 blocks * 256 thr * 4 edges = 640000
#define SB_WPRE 512            // wprep:   512 blocks * 256 = 131072 elements
#define SB_XIN  2500           // xin:     2500 blocks * 16 nodes = 40000

typedef __bf16 bf16x8 __attribute__((ext_vector_type(8)));
typedef float  f32x4  __attribute__((ext_vector_type(4)));
typedef float  f32x2  __attribute__((ext_vector_type(2)));

__device__ inline unsigned short f2bf(float f) {
    __hip_bfloat16 b = __float2bfloat16(f);
    return *(unsigned short*)&b;
}
__device__ inline float bf2f(unsigned short u) {
    __hip_bfloat16 b = *(__hip_bfloat16*)&u;
    return __bfloat162float(b);
}

// ---- setup mega-kernel: [scatter | wprep(W-fold) | xin] by block range ----
// R1-proven 32-VGPR form (R6's LDS-atomic rowmax caused 4.9M bank conflicts,
// occupancy 65->35%). xin additionally reduces a block max of x0 into
// gmaxb[0] via shuffle + ONE atomic per wave (no LDS atomics).
__global__ __launch_bounds__(256) void k_setup(
        const int* __restrict__ row, const int* __restrict__ col,
        const float* __restrict__ w, int* __restrict__ cnt,
        unsigned int* __restrict__ bucket,
        const float* __restrict__ Wconv, unsigned short* __restrict__ Wtbf,
        const float* __restrict__ x, const float* __restrict__ Win,
        const float* __restrict__ bin,
        unsigned short* __restrict__ x0bf, int* __restrict__ gmaxb) {
    __shared__ float sW[H * FIN];      // used by xin branch only (16.9 KB)
    __shared__ float sx[16][FIN];
    int b = blockIdx.x, t = threadIdx.x;

    if (b < SB_SCAT) {
        // bucket scatter: 4 independent chains/thread; record = [bf16 w | col]
        int e0 = (b * 256 + t) * 4;
        int r[4], pos[4];
        unsigned int rec[4];
        #pragma unroll
        for (int i = 0; i < 4; i++) {
            int e = e0 + i;
            r[i] = row[e];
            unsigned int wb = f2bf((1.0f - ALPHA) * w[e]);
            rec[i] = (wb << 16) | (unsigned int)col[e];
        }
        #pragma unroll
        for (int i = 0; i < 4; i++) pos[i] = atomicAdd(&cnt[r[i]], 1);
        #pragma unroll
        for (int i = 0; i < 4; i++) bucket[(size_t)r[i] * CAP + pos[i]] = rec[i];
        return;
    }
    if (b < SB_SCAT + SB_WPRE) {
        // W' = (1-beta)*I + beta*W, transposed to [l][j][k], bf16.
        int idx = (b - SB_SCAT) * 256 + t;        // = l*16384 + k*128 + j
        int l = idx >> 14;
        int rem = idx & 16383;
        int k = rem >> 7, j = rem & 127;
        float beta = logf(THETA / (float)(l + 1) + 1.0f);
        float v = beta * Wconv[idx];
        if (j == k) v += 1.0f - beta;
        Wtbf[l * 16384 + j * 128 + k] = f2bf(v);
        return;
    }
    {
        // x0 = relu(x @ W_in^T + b_in) -> bf16; block max -> gmaxb[0]
        int n0 = (b - SB_SCAT - SB_WPRE) * 16;
        for (int i = t; i < H * FIN; i += 256) sW[i] = Win[i];
        for (int i = t; i < 16 * FIN; i += 256)
            sx[i / FIN][i % FIN] = x[(size_t)(n0 + i / FIN) * FIN + (i % FIN)];
        __syncthreads();
        int f = t % H;
        int l0 = t / H;
        float bv = bin[f];
        float tmax = 0.f;
        for (int lo = l0; lo < 16; lo += 2) {
            float acc = bv;
            #pragma unroll
            for (int k = 0; k < FIN; k++) acc += sx[lo][k] * sW[f * FIN + k];
            acc = fmaxf(acc, 0.f);
            tmax = fmaxf(tmax, acc);
            x0bf[(size_t)(n0 + lo) * H + f] = f2bf(acc);
        }
        #pragma unroll
        for (int off = 1; off < 64; off <<= 1)
            tmax = fmaxf(tmax, __shfl_xor(tmax, off));
        if ((t & 63) == 0) atomicMax(&gmaxb[0], __float_as_int(tmax));
    }
}

// ---- layer 0: bf16 gather from x0 (R1-proven phase 1) -----------------
// epilogue writes hbf (bf16 residual) + fp8 replica (scale 448/(16*gmax[0]))
// + block max of h_0 into gmaxb[1].
__global__ __launch_bounds__(256) void k_layer0(
        const int* __restrict__ cnt, const unsigned int* __restrict__ bucket,
        const unsigned short* __restrict__ x0bf,
        const unsigned short* __restrict__ Wt,
        unsigned short* __restrict__ hbf,
        unsigned char* __restrict__ f8out, int* __restrict__ gmaxb) {
    __shared__ __align__(16) char smem[16896];   // bf16 xx[32][136] / f32 acc[32][132]

    int t = threadIdx.x;
    int wv = t >> 6, lane = t & 63;
    int rbase = blockIdx.x * 32;

    // ---------------- phase 1: bf16 spmm into LDS ----------------
    {
        int slot = lane >> 4;              // 0..3: edge within a group of 4
        int fid  = lane & 15;              // feature block: features fid*8..+7
        for (int i = 0; i < 8; i++) {
            int rloc = wv * 8 + i;
            int row  = rbase + rloc;
            int deg  = cnt[row];
            const unsigned int* ep = bucket + (size_t)row * CAP;
            float acc[8] = {0,0,0,0,0,0,0,0};

            for (int e = 0; e < deg; e += 16) {
                unsigned int u[4];
                uint4 q[4];
                #pragma unroll
                for (int k = 0; k < 4; k++) {
                    int ei = e + k * 4 + slot;           // < CAP always
                    unsigned int uu = ep[ei];
                    u[k] = (ei < deg) ? uu : 0u;
                }
                #pragma unroll
                for (int k = 0; k < 4; k++)
                    q[k] = *(const uint4*)(x0bf + (size_t)(u[k] & 0xffffu) * H + fid * 8);
                #pragma unroll
                for (int k = 0; k < 4; k++) {
                    float w = bf2f((unsigned short)(u[k] >> 16));
                    acc[0] += w * bf2f((unsigned short)(q[k].x & 0xffffu));
                    acc[1] += w * bf2f((unsigned short)(q[k].x >> 16));
                    acc[2] += w * bf2f((unsigned short)(q[k].y & 0xffffu));
                    acc[3] += w * bf2f((unsigned short)(q[k].y >> 16));
                    acc[4] += w * bf2f((unsigned short)(q[k].z & 0xffffu));
                    acc[5] += w * bf2f((unsigned short)(q[k].z >> 16));
                    acc[6] += w * bf2f((unsigned short)(q[k].w & 0xffffu));
                    acc[7] += w * bf2f((unsigned short)(q[k].w >> 16));
                }
            }
            #pragma unroll
            for (int j = 0; j < 8; j++) {
                acc[j] += __shfl_xor(acc[j], 16);
                acc[j] += __shfl_xor(acc[j], 32);
            }
            if (slot == 0) {               // lanes 0..15 hold the full row
                uint4 xq = *(const uint4*)(x0bf + (size_t)row * H + fid * 8);
                float o0 = acc[0] + ALPHA * bf2f((unsigned short)(xq.x & 0xffffu));
                float o1 = acc[1] + ALPHA * bf2f((unsigned short)(xq.x >> 16));
                float o2 = acc[2] + ALPHA * bf2f((unsigned short)(xq.y & 0xffffu));
                float o3 = acc[3] + ALPHA * bf2f((unsigned short)(xq.y >> 16));
                float o4 = acc[4] + ALPHA * bf2f((unsigned short)(xq.z & 0xffffu));
                float o5 = acc[5] + ALPHA * bf2f((unsigned short)(xq.z >> 16));
                float o6 = acc[6] + ALPHA * bf2f((unsigned short)(xq.w & 0xffffu));
                float o7 = acc[7] + ALPHA * bf2f((unsigned short)(xq.w >> 16));
                uint4 r;
                r.x = (unsigned int)f2bf(o0) | ((unsigned int)f2bf(o1) << 16);
                r.y = (unsigned int)f2bf(o2) | ((unsigned int)f2bf(o3) << 16);
                r.z = (unsigned int)f2bf(o4) | ((unsigned int)f2bf(o5) << 16);
                r.w = (unsigned int)f2bf(o6) | ((unsigned int)f2bf(o7) << 16);
                *(uint4*)(smem + (size_t)rloc * 272 + fid * 16) = r;
            }
        }
    }
    __syncthreads();

    // ---------------- phase 2: MFMA GEMM from LDS ----------------
    int quad = lane >> 4, l16 = lane & 15;
    int rh = (wv >> 1) * 16;
    int ch = (wv & 1) * 64;
    f32x4 acc2[4];
    #pragma unroll
    for (int j = 0; j < 4; j++) acc2[j] = (f32x4){0.f, 0.f, 0.f, 0.f};
    #pragma unroll
    for (int k0 = 0; k0 < 4; k0++) {
        bf16x8 av = *(const bf16x8*)(smem + (size_t)(rh + l16) * 272 + k0 * 64 + quad * 16);
        #pragma unroll
        for (int j = 0; j < 4; j++) {
            bf16x8 bv = *(const bf16x8*)(Wt + (size_t)(ch + j * 16 + l16) * H + k0 * 32 + quad * 8);
            acc2[j] = __builtin_amdgcn_mfma_f32_16x16x32_bf16(av, bv, acc2[j], 0, 0, 0);
        }
    }
    __syncthreads();

    // ---------------- phase 3a: acc -> LDS fp32 ----------------
    float* facc = (float*)smem;
    #pragma unroll
    for (int j = 0; j < 4; j++) {
        #pragma unroll
        for (int r = 0; r < 4; r++)
            facc[(rh + quad * 4 + r) * 132 + ch + j * 16 + l16] = acc2[j][r];
    }
    __syncthreads();

    // ---------------- phase 3b: epilogue: residual + fp8 quant ----------
    float g0 = __int_as_float(gmaxb[0]);
    float Q = g0 > 0.f ? 448.f / (HEADROOM * g0) : 0.f;
    int cb = (t & 15) * 8;
    float rmax = 0.f;
    #pragma unroll
    for (int p = 0; p < 2; p++) {
        int rloc = p * 16 + (t >> 4);
        int row  = rbase + rloc;
        const float* fr = facc + rloc * 132 + cb;
        f32x4 a0 = *(const f32x4*)fr;
        f32x4 a1 = *(const f32x4*)(fr + 4);
        uint4 hq = *(const uint4*)(x0bf + (size_t)row * H + cb);
        float hv[8];
        hv[0] = bf2f((unsigned short)(hq.x & 0xffffu)) + fmaxf(a0[0], 0.f);
        hv[1] = bf2f((unsigned short)(hq.x >> 16))     + fmaxf(a0[1], 0.f);
        hv[2] = bf2f((unsigned short)(hq.y & 0xffffu)) + fmaxf(a0[2], 0.f);
        hv[3] = bf2f((unsigned short)(hq.y >> 16))     + fmaxf(a0[3], 0.f);
        hv[4] = bf2f((unsigned short)(hq.z & 0xffffu)) + fmaxf(a1[0], 0.f);
        hv[5] = bf2f((unsigned short)(hq.z >> 16))     + fmaxf(a1[1], 0.f);
        hv[6] = bf2f((unsigned short)(hq.w & 0xffffu)) + fmaxf(a1[2], 0.f);
        hv[7] = bf2f((unsigned short)(hq.w >> 16))     + fmaxf(a1[3], 0.f);

        uint4 rr;
        rr.x = (unsigned int)f2bf(hv[0]) | ((unsigned int)f2bf(hv[1]) << 16);
        rr.y = (unsigned int)f2bf(hv[2]) | ((unsigned int)f2bf(hv[3]) << 16);
        rr.z = (unsigned int)f2bf(hv[4]) | ((unsigned int)f2bf(hv[5]) << 16);
        rr.w = (unsigned int)f2bf(hv[6]) | ((unsigned int)f2bf(hv[7]) << 16);
        *(uint4*)(hbf + (size_t)row * H + cb) = rr;

        int d0 = __builtin_amdgcn_cvt_pk_fp8_f32(hv[0] * Q, hv[1] * Q, 0, false);
        d0     = __builtin_amdgcn_cvt_pk_fp8_f32(hv[2] * Q, hv[3] * Q, d0, true);
        int d1 = __builtin_amdgcn_cvt_pk_fp8_f32(hv[4] * Q, hv[5] * Q, 0, false);
        d1     = __builtin_amdgcn_cvt_pk_fp8_f32(hv[6] * Q, hv[7] * Q, d1, true);
        uint2 f8v; f8v.x = (unsigned int)d0; f8v.y = (unsigned int)d1;
        *(uint2*)(f8out + (size_t)row * H + cb) = f8v;

        #pragma unroll
        for (int j = 0; j < 8; j++) rmax = fmaxf(rmax, hv[j]);
    }
    #pragma unroll
    for (int off = 1; off < 64; off <<= 1)
        rmax = fmaxf(rmax, __shfl_xor(rmax, off));
    if ((t & 63) == 0) atomicMax(&gmaxb[1], __float_as_int(rmax));
}

// ---- layers 1..7: fp8 gather (no per-edge scale traffic) ---------------
// Dequant: ONE uniform multiply (16*gmax[li-1]/448) folded at reduce end.
// Epilogue: residual bf16 in place; quant h_li with 448/(16*gmax[li]);
// block max -> gmaxb[li+1]. Last layer: output projection instead.
__global__ __launch_bounds__(256) void k_layerf8(
        const int* __restrict__ cnt, const unsigned int* __restrict__ bucket,
        const unsigned char* __restrict__ f8in,
        unsigned char* __restrict__ f8out,
        unsigned short* __restrict__ hbf,
        const unsigned short* __restrict__ x0bf,
        const unsigned short* __restrict__ Wt,
        int* __restrict__ gmaxb, int li,
        const float* __restrict__ Wout, const float* __restrict__ bout,
        float* __restrict__ out, int do_out) {
    __shared__ __align__(16) char smem[16896];   // bf16 xx[32][136] / f32 acc[32][132]

    int t = threadIdx.x;
    int wv = t >> 6, lane = t & 63;
    int rbase = blockIdx.x * 32;

    float gin = __int_as_float(gmaxb[li - 1]);
    float D = gin > 0.f ? (HEADROOM / 448.f) * gin : 0.f;   // dequant, uniform

    // ---------------- phase 1: fp8 spmm into LDS ----------------
    {
        int slot = lane >> 3;              // 0..7: edge within a group of 8
        int fid  = lane & 7;               // feature block: features fid*16..+15
        for (int i = 0; i < 8; i++) {
            int rloc = wv * 8 + i;
            int row  = rbase + rloc;
            int deg  = cnt[row];
            const unsigned int* ep = bucket + (size_t)row * CAP;
            float acc[16];
            #pragma unroll
            for (int j = 0; j < 16; j++) acc[j] = 0.f;

            for (int e = 0; e < deg; e += 16) {
                unsigned int u[2];
                uint4 q[2];
                #pragma unroll
                for (int k = 0; k < 2; k++) {
                    int ei = e + k * 8 + slot;           // < CAP always
                    unsigned int uu = ep[ei];
                    u[k] = (ei < deg) ? uu : 0u;         // u=0 -> w=0
                }
                #pragma unroll
                for (int k = 0; k < 2; k++)
                    q[k] = *(const uint4*)(f8in + (size_t)(u[k] & 0xffffu) * H + fid * 16);
                #pragma unroll
                for (int k = 0; k < 2; k++) {
                    float w = bf2f((unsigned short)(u[k] >> 16));
                    unsigned int dw[4] = {q[k].x, q[k].y, q[k].z, q[k].w};
                    #pragma unroll
                    for (int d = 0; d < 4; d++) {
                        f32x2 lo = __builtin_amdgcn_cvt_pk_f32_fp8(dw[d], false);
                        f32x2 hi = __builtin_amdgcn_cvt_pk_f32_fp8(dw[d], true);
                        acc[d * 4 + 0] += w * lo.x;
                        acc[d * 4 + 1] += w * lo.y;
                        acc[d * 4 + 2] += w * hi.x;
                        acc[d * 4 + 3] += w * hi.y;
                    }
                }
            }
            #pragma unroll
            for (int j = 0; j < 16; j++) {
                acc[j] += __shfl_xor(acc[j], 8);
                acc[j] += __shfl_xor(acc[j], 16);
                acc[j] += __shfl_xor(acc[j], 32);
            }
            if (slot == 0) {               // lanes 0..7 hold the full row
                uint4 xa = *(const uint4*)(x0bf + (size_t)row * H + fid * 16);
                uint4 xb = *(const uint4*)(x0bf + (size_t)row * H + fid * 16 + 8);
                unsigned int xw[8] = {xa.x, xa.y, xa.z, xa.w, xb.x, xb.y, xb.z, xb.w};
                uint4 r0, r1;
                unsigned int rr[8];
                #pragma unroll
                for (int p = 0; p < 8; p++) {
                    float o0 = acc[p * 2 + 0] * D + ALPHA * bf2f((unsigned short)(xw[p] & 0xffffu));
                    float o1 = acc[p * 2 + 1] * D + ALPHA * bf2f((unsigned short)(xw[p] >> 16));
                    rr[p] = (unsigned int)f2bf(o0) | ((unsigned int)f2bf(o1) << 16);
                }
                r0.x = rr[0]; r0.y = rr[1]; r0.z = rr[2]; r0.w = rr[3];
                r1.x = rr[4]; r1.y = rr[5]; r1.z = rr[6]; r1.w = rr[7];
                *(uint4*)(smem + (size_t)rloc * 272 + fid * 32) = r0;
                *(uint4*)(smem + (size_t)rloc * 272 + fid * 32 + 16) = r1;
            }
        }
    }
    __syncthreads();

    // ---------------- phase 2: MFMA GEMM from LDS ----------------
    int quad = lane >> 4, l16 = lane & 15;
    int rh = (wv >> 1) * 16;
    int ch = (wv & 1) * 64;
    f32x4 acc2[4];
    #pragma unroll
    for (int j = 0; j < 4; j++) acc2[j] = (f32x4){0.f, 0.f, 0.f, 0.f};
    #pragma unroll
    for (int k0 = 0; k0 < 4; k0++) {
        bf16x8 av = *(const bf16x8*)(smem + (size_t)(rh + l16) * 272 + k0 * 64 + quad * 16);
        #pragma unroll
        for (int j = 0; j < 4; j++) {
            bf16x8 bv = *(const bf16x8*)(Wt + (size_t)(ch + j * 16 + l16) * H + k0 * 32 + quad * 8);
            acc2[j] = __builtin_amdgcn_mfma_f32_16x16x32_bf16(av, bv, acc2[j], 0, 0, 0);
        }
    }
    __syncthreads();

    // ---------------- phase 3a: acc -> LDS fp32 ----------------
    float* facc = (float*)smem;
    #pragma unroll
    for (int j = 0; j < 4; j++) {
        #pragma unroll
        for (int r = 0; r < 4; r++)
            facc[(rh + quad * 4 + r) * 132 + ch + j * 16 + l16] = acc2[j][r];
    }
    __syncthreads();

    // ---------------- phase 3b: coalesced epilogue ----------------
    float gq = __int_as_float(gmaxb[li]);
    float Q = gq > 0.f ? 448.f / (HEADROOM * gq) : 0.f;     // quant, uniform
    int cb = (t & 15) * 8;
    float rmax = 0.f;
    #pragma unroll
    for (int p = 0; p < 2; p++) {
        int rloc = p * 16 + (t >> 4);
        int row  = rbase + rloc;
        const float* fr = facc + rloc * 132 + cb;
        f32x4 a0 = *(const f32x4*)fr;
        f32x4 a1 = *(const f32x4*)(fr + 4);
        uint4 hq = *(const uint4*)(hbf + (size_t)row * H + cb);
        float hv[8];
        hv[0] = bf2f((unsigned short)(hq.x & 0xffffu)) + fmaxf(a0[0], 0.f);
        hv[1] = bf2f((unsigned short)(hq.x >> 16))     + fmaxf(a0[1], 0.f);
        hv[2] = bf2f((unsigned short)(hq.y & 0xffffu)) + fmaxf(a0[2], 0.f);
        hv[3] = bf2f((unsigned short)(hq.y >> 16))     + fmaxf(a0[3], 0.f);
        hv[4] = bf2f((unsigned short)(hq.z & 0xffffu)) + fmaxf(a1[0], 0.f);
        hv[5] = bf2f((unsigned short)(hq.z >> 16))     + fmaxf(a1[1], 0.f);
        hv[6] = bf2f((unsigned short)(hq.w & 0xffffu)) + fmaxf(a1[2], 0.f);
        hv[7] = bf2f((unsigned short)(hq.w >> 16))     + fmaxf(a1[3], 0.f);

        if (!do_out) {
            uint4 rr;
            rr.x = (unsigned int)f2bf(hv[0]) | ((unsigned int)f2bf(hv[1]) << 16);
            rr.y = (unsigned int)f2bf(hv[2]) | ((unsigned int)f2bf(hv[3]) << 16);
            rr.z = (unsigned int)f2bf(hv[4]) | ((unsigned int)f2bf(hv[5]) << 16);
            rr.w = (unsigned int)f2bf(hv[6]) | ((unsigned int)f2bf(hv[7]) << 16);
            *(uint4*)(hbf + (size_t)row * H + cb) = rr;
            int d0 = __builtin_amdgcn_cvt_pk_fp8_f32(hv[0] * Q, hv[1] * Q, 0, false);
            d0     = __builtin_amdgcn_cvt_pk_fp8_f32(hv[2] * Q, hv[3] * Q, d0, true);
            int d1 = __builtin_amdgcn_cvt_pk_fp8_f32(hv[4] * Q, hv[5] * Q, 0, false);
            d1     = __builtin_amdgcn_cvt_pk_fp8_f32(hv[6] * Q, hv[7] * Q, d1, true);
            uint2 f8v; f8v.x = (unsigned int)d0; f8v.y = (unsigned int)d1;
            *(uint2*)(f8out + (size_t)row * H + cb) = f8v;
            #pragma unroll
            for (int j = 0; j < 8; j++) rmax = fmaxf(rmax, hv[j]);
        } else {
            float p0 = 0.f, p1 = 0.f, p2 = 0.f;
            #pragma unroll
            for (int i2 = 0; i2 < 8; i2++) {
                float h = hv[i2];
                p0 += h * Wout[cb + i2];
                p1 += h * Wout[H + cb + i2];
                p2 += h * Wout[2 * H + cb + i2];
            }
            #pragma unroll
            for (int off = 1; off < 16; off <<= 1) {
                p0 += __shfl_xor(p0, off);
                p1 += __shfl_xor(p1, off);
                p2 += __shfl_xor(p2, off);
            }
            if ((t & 15) == 0) {
                out[(size_t)row * 3 + 0] = p0 + bout[0];
                out[(size_t)row * 3 + 1] = p1 + bout[1];
                out[(size_t)row * 3 + 2] = p2 + bout[2];
            }
        }
    }
    if (!do_out) {
        #pragma unroll
        for (int off = 1; off < 64; off <<= 1)
            rmax = fmaxf(rmax, __shfl_xor(rmax, off));
        if ((t & 63) == 0) atomicMax(&gmaxb[li + 1], __float_as_int(rmax));
    }
}

extern "C" void kernel_launch(void* const* d_in, const int* in_sizes, int n_in,
                              void* d_out, int out_size, void* d_ws, size_t ws_size,
                              hipStream_t stream) {
    const float* x     = (const float*)d_in[0];
    const int*   erow  = (const int*)  d_in[1];
    const int*   ecol  = (const int*)  d_in[2];
    const float* ew    = (const float*)d_in[3];
    const float* Win   = (const float*)d_in[4];
    const float* bin   = (const float*)d_in[5];
    const float* Wout  = (const float*)d_in[6];
    const float* bout  = (const float*)d_in[7];
    const float* Wconv = (const float*)d_in[8];
    float* out = (float*)d_out;

    char* ws = (char*)d_ws;
    const size_t NHb = (size_t)N_NODES * H * sizeof(unsigned short);  // 10,240,000
    const size_t NH8 = (size_t)N_NODES * H;                           //  5,120,000
    unsigned short* x0bf = (unsigned short*)(ws);
    unsigned short* hbf  = (unsigned short*)(ws + NHb);     // bf16 residual, in-place
    unsigned char*  hf8A = (unsigned char*)(ws + 2 * NHb);
    unsigned char*  hf8B = (unsigned char*)(ws + 2 * NHb + NH8);
    char* p = ws + 2 * NHb + 2 * NH8;
    unsigned short* Wtbf = (unsigned short*)p;  p += 8 * H * H * 2;   // 262,144
    int* cnt   = (int*)p;                       // N ints
    int* gmaxb = (int*)(p + 160000);            // 16 ints in cnt's pad
    p += 160256;
    unsigned int* bucket = (unsigned int*)p;    // N * CAP * 4 = 15,360,000 B

    // zero counters + gmax slots, then one mega-dispatch
    hipMemsetAsync(cnt, 0, 160256, stream);
    k_setup<<<SB_SCAT + SB_WPRE + SB_XIN, 256, 0, stream>>>(
        erow, ecol, ew, cnt, bucket, Wconv, Wtbf, x, Win, bin, x0bf, gmaxb);

    // layer 0: bf16 gather from x0; writes hbf + fp8 replica (hf8A) + gmax[1]
    k_layer0<<<N_NODES / 32, 256, 0, stream>>>(
        cnt, bucket, x0bf, Wtbf, hbf, hf8A, gmaxb);

    // layers 1..7: fp8 gather; replica ping-pongs (layer l reads buf[(l-1)&1])
    for (int l = 1; l < NLAYERS; l++) {
        const unsigned char* f8in  = ((l - 1) & 1) ? hf8B : hf8A;
        unsigned char*       f8out = ((l - 1) & 1) ? hf8A : hf8B;
        k_layerf8<<<N_NODES / 32, 256, 0, stream>>>(
            cnt, bucket, f8in, f8out, hbf, x0bf,
            Wtbf + (size_t)l * H * H, gmaxb, l, Wout, bout, out,
            (l == NLAYERS - 1) ? 1 : 0);
    }
}

// Round 8
// 893.033 us; speedup vs baseline: 1.0104x; 1.0104x over previous
//
#include <hip/hip_runtime.h>
#include <hip/hip_bf16.h>
#include <math.h>

#define N_NODES 40000
#define NE      640000
#define FIN     33
#define H       128
#define COUT    3
#define NLAYERS 8
#define ALPHA   0.1f
#define THETA   0.5f
#define CAP     96             // max bucket capacity; deg ~ Poisson(16), P(>96) ~ 1e-40
#define HEADROOM 16.0f         // fp8 scale headroom: covers <16x single-layer growth

// setup mega-kernel block ranges (scatter FIRST — longest per-block branch)
#define SB_SCAT 625            // scatter: 625 blocks * 256 thr * 4 edges = 640000
#define SB_WPRE 512            // wprep:   512 blocks * 256 = 131072 elements
#define SB_XIN  2500           // xin:     2500 blocks * 16 nodes = 40000

typedef __bf16 bf16x8 __attribute__((ext_vector_type(8)));
typedef float  f32x4  __attribute__((ext_vector_type(4)));
typedef float  f32x2  __attribute__((ext_vector_type(2)));

__device__ inline unsigned short f2bf(float f) {
    __hip_bfloat16 b = __float2bfloat16(f);
    return *(unsigned short*)&b;
}
__device__ inline float bf2f(unsigned short u) {
    __hip_bfloat16 b = *(__hip_bfloat16*)&u;
    return __bfloat162float(b);
}

// ---- setup mega-kernel: [scatter | wprep(W-fold) | xin] by block range ----
// R1-proven 32-VGPR form. xin additionally reduces a block max of x0 into
// gmaxb[0] via shuffle + ONE atomic per wave (no LDS atomics).
__global__ __launch_bounds__(256) void k_setup(
        const int* __restrict__ row, const int* __restrict__ col,
        const float* __restrict__ w, int* __restrict__ cnt,
        unsigned int* __restrict__ bucket,
        const float* __restrict__ Wconv, unsigned short* __restrict__ Wtbf,
        const float* __restrict__ x, const float* __restrict__ Win,
        const float* __restrict__ bin,
        unsigned short* __restrict__ x0bf, int* __restrict__ gmaxb) {
    __shared__ float sW[H * FIN];      // used by xin branch only (16.9 KB)
    __shared__ float sx[16][FIN];
    int b = blockIdx.x, t = threadIdx.x;

    if (b < SB_SCAT) {
        // bucket scatter: 4 independent chains/thread; record = [bf16 w | col]
        int e0 = (b * 256 + t) * 4;
        int r[4], pos[4];
        unsigned int rec[4];
        #pragma unroll
        for (int i = 0; i < 4; i++) {
            int e = e0 + i;
            r[i] = row[e];
            unsigned int wb = f2bf((1.0f - ALPHA) * w[e]);
            rec[i] = (wb << 16) | (unsigned int)col[e];
        }
        #pragma unroll
        for (int i = 0; i < 4; i++) pos[i] = atomicAdd(&cnt[r[i]], 1);
        #pragma unroll
        for (int i = 0; i < 4; i++) bucket[(size_t)r[i] * CAP + pos[i]] = rec[i];
        return;
    }
    if (b < SB_SCAT + SB_WPRE) {
        // W' = (1-beta)*I + beta*W, transposed to [l][j][k], bf16.
        int idx = (b - SB_SCAT) * 256 + t;        // = l*16384 + k*128 + j
        int l = idx >> 14;
        int rem = idx & 16383;
        int k = rem >> 7, j = rem & 127;
        float beta = logf(THETA / (float)(l + 1) + 1.0f);
        float v = beta * Wconv[idx];
        if (j == k) v += 1.0f - beta;
        Wtbf[l * 16384 + j * 128 + k] = f2bf(v);
        return;
    }
    {
        // x0 = relu(x @ W_in^T + b_in) -> bf16; block max -> gmaxb[0]
        int n0 = (b - SB_SCAT - SB_WPRE) * 16;
        for (int i = t; i < H * FIN; i += 256) sW[i] = Win[i];
        for (int i = t; i < 16 * FIN; i += 256)
            sx[i / FIN][i % FIN] = x[(size_t)(n0 + i / FIN) * FIN + (i % FIN)];
        __syncthreads();
        int f = t % H;
        int l0 = t / H;
        float bv = bin[f];
        float tmax = 0.f;
        for (int lo = l0; lo < 16; lo += 2) {
            float acc = bv;
            #pragma unroll
            for (int k = 0; k < FIN; k++) acc += sx[lo][k] * sW[f * FIN + k];
            acc = fmaxf(acc, 0.f);
            tmax = fmaxf(tmax, acc);
            x0bf[(size_t)(n0 + lo) * H + f] = f2bf(acc);
        }
        #pragma unroll
        for (int off = 1; off < 64; off <<= 1)
            tmax = fmaxf(tmax, __shfl_xor(tmax, off));
        if ((t & 63) == 0) atomicMax(&gmaxb[0], __float_as_int(tmax));
    }
}

// ---- layer 0: bf16 gather from x0 (R1-proven phase 1) -----------------
// epilogue writes hbf (bf16 residual) + fp8 replica (scale 448/(16*gmax[0]))
// + block max of h_0 into gmaxb[1].
__global__ __launch_bounds__(256) void k_layer0(
        const int* __restrict__ cnt, const unsigned int* __restrict__ bucket,
        const unsigned short* __restrict__ x0bf,
        const unsigned short* __restrict__ Wt,
        unsigned short* __restrict__ hbf,
        unsigned char* __restrict__ f8out, int* __restrict__ gmaxb) {
    __shared__ __align__(16) char smem[16896];   // bf16 xx[32][136] / f32 acc[32][132]

    int t = threadIdx.x;
    int wv = t >> 6, lane = t & 63;
    int rbase = blockIdx.x * 32;
    float g0 = __int_as_float(gmaxb[0]);          // load scale once at entry
    float Q = g0 > 0.f ? 448.f / (HEADROOM * g0) : 0.f;

    // ---------------- phase 1: bf16 spmm into LDS ----------------
    {
        int slot = lane >> 4;              // 0..3: edge within a group of 4
        int fid  = lane & 15;              // feature block: features fid*8..+7
        for (int i = 0; i < 8; i++) {
            int rloc = wv * 8 + i;
            int row  = rbase + rloc;
            int deg  = cnt[row];
            const unsigned int* ep = bucket + (size_t)row * CAP;
            float acc[8] = {0,0,0,0,0,0,0,0};

            for (int e = 0; e < deg; e += 16) {
                unsigned int u[4];
                uint4 q[4];
                #pragma unroll
                for (int k = 0; k < 4; k++) {
                    int ei = e + k * 4 + slot;           // < CAP always
                    unsigned int uu = ep[ei];
                    u[k] = (ei < deg) ? uu : 0u;
                }
                #pragma unroll
                for (int k = 0; k < 4; k++)
                    q[k] = *(const uint4*)(x0bf + (size_t)(u[k] & 0xffffu) * H + fid * 8);
                #pragma unroll
                for (int k = 0; k < 4; k++) {
                    float w = bf2f((unsigned short)(u[k] >> 16));
                    acc[0] += w * bf2f((unsigned short)(q[k].x & 0xffffu));
                    acc[1] += w * bf2f((unsigned short)(q[k].x >> 16));
                    acc[2] += w * bf2f((unsigned short)(q[k].y & 0xffffu));
                    acc[3] += w * bf2f((unsigned short)(q[k].y >> 16));
                    acc[4] += w * bf2f((unsigned short)(q[k].z & 0xffffu));
                    acc[5] += w * bf2f((unsigned short)(q[k].z >> 16));
                    acc[6] += w * bf2f((unsigned short)(q[k].w & 0xffffu));
                    acc[7] += w * bf2f((unsigned short)(q[k].w >> 16));
                }
            }
            #pragma unroll
            for (int j = 0; j < 8; j++) {
                acc[j] += __shfl_xor(acc[j], 16);
                acc[j] += __shfl_xor(acc[j], 32);
            }
            if (slot == 0) {               // lanes 0..15 hold the full row
                uint4 xq = *(const uint4*)(x0bf + (size_t)row * H + fid * 8);
                float o0 = acc[0] + ALPHA * bf2f((unsigned short)(xq.x & 0xffffu));
                float o1 = acc[1] + ALPHA * bf2f((unsigned short)(xq.x >> 16));
                float o2 = acc[2] + ALPHA * bf2f((unsigned short)(xq.y & 0xffffu));
                float o3 = acc[3] + ALPHA * bf2f((unsigned short)(xq.y >> 16));
                float o4 = acc[4] + ALPHA * bf2f((unsigned short)(xq.z & 0xffffu));
                float o5 = acc[5] + ALPHA * bf2f((unsigned short)(xq.z >> 16));
                float o6 = acc[6] + ALPHA * bf2f((unsigned short)(xq.w & 0xffffu));
                float o7 = acc[7] + ALPHA * bf2f((unsigned short)(xq.w >> 16));
                uint4 r;
                r.x = (unsigned int)f2bf(o0) | ((unsigned int)f2bf(o1) << 16);
                r.y = (unsigned int)f2bf(o2) | ((unsigned int)f2bf(o3) << 16);
                r.z = (unsigned int)f2bf(o4) | ((unsigned int)f2bf(o5) << 16);
                r.w = (unsigned int)f2bf(o6) | ((unsigned int)f2bf(o7) << 16);
                *(uint4*)(smem + (size_t)rloc * 272 + fid * 16) = r;
            }
        }
    }
    __syncthreads();

    // ---------------- phase 2: MFMA GEMM from LDS ----------------
    int quad = lane >> 4, l16 = lane & 15;
    int rh = (wv >> 1) * 16;
    int ch = (wv & 1) * 64;
    f32x4 acc2[4];
    #pragma unroll
    for (int j = 0; j < 4; j++) acc2[j] = (f32x4){0.f, 0.f, 0.f, 0.f};
    #pragma unroll
    for (int k0 = 0; k0 < 4; k0++) {
        bf16x8 av = *(const bf16x8*)(smem + (size_t)(rh + l16) * 272 + k0 * 64 + quad * 16);
        #pragma unroll
        for (int j = 0; j < 4; j++) {
            bf16x8 bv = *(const bf16x8*)(Wt + (size_t)(ch + j * 16 + l16) * H + k0 * 32 + quad * 8);
            acc2[j] = __builtin_amdgcn_mfma_f32_16x16x32_bf16(av, bv, acc2[j], 0, 0, 0);
        }
    }
    __syncthreads();

    // ---------------- phase 3a: acc -> LDS fp32 ----------------
    float* facc = (float*)smem;
    #pragma unroll
    for (int j = 0; j < 4; j++) {
        #pragma unroll
        for (int r = 0; r < 4; r++)
            facc[(rh + quad * 4 + r) * 132 + ch + j * 16 + l16] = acc2[j][r];
    }
    __syncthreads();

    // ---------------- phase 3b: epilogue: residual + fp8 quant ----------
    int cb = (t & 15) * 8;
    float rmax = 0.f;
    #pragma unroll
    for (int p = 0; p < 2; p++) {
        int rloc = p * 16 + (t >> 4);
        int row  = rbase + rloc;
        const float* fr = facc + rloc * 132 + cb;
        f32x4 a0 = *(const f32x4*)fr;
        f32x4 a1 = *(const f32x4*)(fr + 4);
        uint4 hq = *(const uint4*)(x0bf + (size_t)row * H + cb);
        float hv[8];
        hv[0] = bf2f((unsigned short)(hq.x & 0xffffu)) + fmaxf(a0[0], 0.f);
        hv[1] = bf2f((unsigned short)(hq.x >> 16))     + fmaxf(a0[1], 0.f);
        hv[2] = bf2f((unsigned short)(hq.y & 0xffffu)) + fmaxf(a0[2], 0.f);
        hv[3] = bf2f((unsigned short)(hq.y >> 16))     + fmaxf(a0[3], 0.f);
        hv[4] = bf2f((unsigned short)(hq.z & 0xffffu)) + fmaxf(a1[0], 0.f);
        hv[5] = bf2f((unsigned short)(hq.z >> 16))     + fmaxf(a1[1], 0.f);
        hv[6] = bf2f((unsigned short)(hq.w & 0xffffu)) + fmaxf(a1[2], 0.f);
        hv[7] = bf2f((unsigned short)(hq.w >> 16))     + fmaxf(a1[3], 0.f);

        uint4 rr;
        rr.x = (unsigned int)f2bf(hv[0]) | ((unsigned int)f2bf(hv[1]) << 16);
        rr.y = (unsigned int)f2bf(hv[2]) | ((unsigned int)f2bf(hv[3]) << 16);
        rr.z = (unsigned int)f2bf(hv[4]) | ((unsigned int)f2bf(hv[5]) << 16);
        rr.w = (unsigned int)f2bf(hv[6]) | ((unsigned int)f2bf(hv[7]) << 16);
        *(uint4*)(hbf + (size_t)row * H + cb) = rr;

        int d0 = __builtin_amdgcn_cvt_pk_fp8_f32(hv[0] * Q, hv[1] * Q, 0, false);
        d0     = __builtin_amdgcn_cvt_pk_fp8_f32(hv[2] * Q, hv[3] * Q, d0, true);
        int d1 = __builtin_amdgcn_cvt_pk_fp8_f32(hv[4] * Q, hv[5] * Q, 0, false);
        d1     = __builtin_amdgcn_cvt_pk_fp8_f32(hv[6] * Q, hv[7] * Q, d1, true);
        uint2 f8v; f8v.x = (unsigned int)d0; f8v.y = (unsigned int)d1;
        *(uint2*)(f8out + (size_t)row * H + cb) = f8v;

        #pragma unroll
        for (int j = 0; j < 8; j++) rmax = fmaxf(rmax, hv[j]);
    }
    #pragma unroll
    for (int off = 1; off < 64; off <<= 1)
        rmax = fmaxf(rmax, __shfl_xor(rmax, off));
    if ((t & 63) == 0) atomicMax(&gmaxb[1], __float_as_int(rmax));
}

// ---- layers 1..7: fp8 gather (2 cachelines/edge, no scale traffic) -----
// Dequant: ONE uniform multiply (16*gmax[li-1]/448) folded at reduce end.
// Epilogue: residual bf16 in place; quant h_li with 448/(16*gmax[li]);
// block max -> gmaxb[li+1]. Last layer: output projection instead.
__global__ __launch_bounds__(256) void k_layerf8(
        const int* __restrict__ cnt, const unsigned int* __restrict__ bucket,
        const unsigned char* __restrict__ f8in,
        unsigned char* __restrict__ f8out,
        unsigned short* __restrict__ hbf,
        const unsigned short* __restrict__ x0bf,
        const unsigned short* __restrict__ Wt,
        int* __restrict__ gmaxb, int li,
        const float* __restrict__ Wout, const float* __restrict__ bout,
        float* __restrict__ out, int do_out) {
    __shared__ __align__(16) char smem[16896];   // bf16 xx[32][136] / f32 acc[32][132]

    int t = threadIdx.x;
    int wv = t >> 6, lane = t & 63;
    int rbase = blockIdx.x * 32;

    // load both scales ONCE at kernel entry (uniform)
    float gin = __int_as_float(gmaxb[li - 1]);
    float D = gin > 0.f ? (HEADROOM / 448.f) * gin : 0.f;   // dequant, uniform
    float gq = __int_as_float(gmaxb[li]);
    float Q = gq > 0.f ? 448.f / (HEADROOM * gq) : 0.f;     // quant, uniform

    // ---------------- phase 1: fp8 spmm into LDS ----------------
    {
        int slot = lane >> 3;              // 0..7: edge within a group of 8
        int fid  = lane & 7;               // feature block: features fid*16..+15
        for (int i = 0; i < 8; i++) {
            int rloc = wv * 8 + i;
            int row  = rbase + rloc;
            int deg  = cnt[row];
            const unsigned int* ep = bucket + (size_t)row * CAP;
            float acc[16];
            #pragma unroll
            for (int j = 0; j < 16; j++) acc[j] = 0.f;

            for (int e = 0; e < deg; e += 16) {
                unsigned int u[2];
                uint4 q[2];
                #pragma unroll
                for (int k = 0; k < 2; k++) {
                    int ei = e + k * 8 + slot;           // < CAP always
                    unsigned int uu = ep[ei];
                    u[k] = (ei < deg) ? uu : 0u;         // u=0 -> w=0
                }
                #pragma unroll
                for (int k = 0; k < 2; k++)
                    q[k] = *(const uint4*)(f8in + (size_t)(u[k] & 0xffffu) * H + fid * 16);
                #pragma unroll
                for (int k = 0; k < 2; k++) {
                    float w = bf2f((unsigned short)(u[k] >> 16));
                    unsigned int dw[4] = {q[k].x, q[k].y, q[k].z, q[k].w};
                    #pragma unroll
                    for (int d = 0; d < 4; d++) {
                        f32x2 lo = __builtin_amdgcn_cvt_pk_f32_fp8(dw[d], false);
                        f32x2 hi = __builtin_amdgcn_cvt_pk_f32_fp8(dw[d], true);
                        acc[d * 4 + 0] += w * lo.x;
                        acc[d * 4 + 1] += w * lo.y;
                        acc[d * 4 + 2] += w * hi.x;
                        acc[d * 4 + 3] += w * hi.y;
                    }
                }
            }
            #pragma unroll
            for (int j = 0; j < 16; j++) {
                acc[j] += __shfl_xor(acc[j], 8);
                acc[j] += __shfl_xor(acc[j], 16);
                acc[j] += __shfl_xor(acc[j], 32);
            }
            if (slot == 0) {               // lanes 0..7 hold the full row
                uint4 xa = *(const uint4*)(x0bf + (size_t)row * H + fid * 16);
                uint4 xb = *(const uint4*)(x0bf + (size_t)row * H + fid * 16 + 8);
                unsigned int xw[8] = {xa.x, xa.y, xa.z, xa.w, xb.x, xb.y, xb.z, xb.w};
                uint4 r0, r1;
                unsigned int rr[8];
                #pragma unroll
                for (int p = 0; p < 8; p++) {
                    float o0 = acc[p * 2 + 0] * D + ALPHA * bf2f((unsigned short)(xw[p] & 0xffffu));
                    float o1 = acc[p * 2 + 1] * D + ALPHA * bf2f((unsigned short)(xw[p] >> 16));
                    rr[p] = (unsigned int)f2bf(o0) | ((unsigned int)f2bf(o1) << 16);
                }
                r0.x = rr[0]; r0.y = rr[1]; r0.z = rr[2]; r0.w = rr[3];
                r1.x = rr[4]; r1.y = rr[5]; r1.z = rr[6]; r1.w = rr[7];
                *(uint4*)(smem + (size_t)rloc * 272 + fid * 32) = r0;
                *(uint4*)(smem + (size_t)rloc * 272 + fid * 32 + 16) = r1;
            }
        }
    }
    __syncthreads();

    // ---------------- phase 2: MFMA GEMM from LDS ----------------
    int quad = lane >> 4, l16 = lane & 15;
    int rh = (wv >> 1) * 16;
    int ch = (wv & 1) * 64;
    f32x4 acc2[4];
    #pragma unroll
    for (int j = 0; j < 4; j++) acc2[j] = (f32x4){0.f, 0.f, 0.f, 0.f};
    #pragma unroll
    for (int k0 = 0; k0 < 4; k0++) {
        bf16x8 av = *(const bf16x8*)(smem + (size_t)(rh + l16) * 272 + k0 * 64 + quad * 16);
        #pragma unroll
        for (int j = 0; j < 4; j++) {
            bf16x8 bv = *(const bf16x8*)(Wt + (size_t)(ch + j * 16 + l16) * H + k0 * 32 + quad * 8);
            acc2[j] = __builtin_amdgcn_mfma_f32_16x16x32_bf16(av, bv, acc2[j], 0, 0, 0);
        }
    }
    __syncthreads();

    // ---------------- phase 3a: acc -> LDS fp32 ----------------
    float* facc = (float*)smem;
    #pragma unroll
    for (int j = 0; j < 4; j++) {
        #pragma unroll
        for (int r = 0; r < 4; r++)
            facc[(rh + quad * 4 + r) * 132 + ch + j * 16 + l16] = acc2[j][r];
    }
    __syncthreads();

    // ---------------- phase 3b: coalesced epilogue ----------------
    int cb = (t & 15) * 8;
    float rmax = 0.f;
    #pragma unroll
    for (int p = 0; p < 2; p++) {
        int rloc = p * 16 + (t >> 4);
        int row  = rbase + rloc;
        const float* fr = facc + rloc * 132 + cb;
        f32x4 a0 = *(const f32x4*)fr;
        f32x4 a1 = *(const f32x4*)(fr + 4);
        uint4 hq = *(const uint4*)(hbf + (size_t)row * H + cb);
        float hv[8];
        hv[0] = bf2f((unsigned short)(hq.x & 0xffffu)) + fmaxf(a0[0], 0.f);
        hv[1] = bf2f((unsigned short)(hq.x >> 16))     + fmaxf(a0[1], 0.f);
        hv[2] = bf2f((unsigned short)(hq.y & 0xffffu)) + fmaxf(a0[2], 0.f);
        hv[3] = bf2f((unsigned short)(hq.y >> 16))     + fmaxf(a0[3], 0.f);
        hv[4] = bf2f((unsigned short)(hq.z & 0xffffu)) + fmaxf(a1[0], 0.f);
        hv[5] = bf2f((unsigned short)(hq.z >> 16))     + fmaxf(a1[1], 0.f);
        hv[6] = bf2f((unsigned short)(hq.w & 0xffffu)) + fmaxf(a1[2], 0.f);
        hv[7] = bf2f((unsigned short)(hq.w >> 16))     + fmaxf(a1[3], 0.f);

        if (!do_out) {
            uint4 rr;
            rr.x = (unsigned int)f2bf(hv[0]) | ((unsigned int)f2bf(hv[1]) << 16);
            rr.y = (unsigned int)f2bf(hv[2]) | ((unsigned int)f2bf(hv[3]) << 16);
            rr.z = (unsigned int)f2bf(hv[4]) | ((unsigned int)f2bf(hv[5]) << 16);
            rr.w = (unsigned int)f2bf(hv[6]) | ((unsigned int)f2bf(hv[7]) << 16);
            *(uint4*)(hbf + (size_t)row * H + cb) = rr;
            int d0 = __builtin_amdgcn_cvt_pk_fp8_f32(hv[0] * Q, hv[1] * Q, 0, false);
            d0     = __builtin_amdgcn_cvt_pk_fp8_f32(hv[2] * Q, hv[3] * Q, d0, true);
            int d1 = __builtin_amdgcn_cvt_pk_fp8_f32(hv[4] * Q, hv[5] * Q, 0, false);
            d1     = __builtin_amdgcn_cvt_pk_fp8_f32(hv[6] * Q, hv[7] * Q, d1, true);
            uint2 f8v; f8v.x = (unsigned int)d0; f8v.y = (unsigned int)d1;
            *(uint2*)(f8out + (size_t)row * H + cb) = f8v;
            #pragma unroll
            for (int j = 0; j < 8; j++) rmax = fmaxf(rmax, hv[j]);
        } else {
            float p0 = 0.f, p1 = 0.f, p2 = 0.f;
            #pragma unroll
            for (int i2 = 0; i2 < 8; i2++) {
                float h = hv[i2];
                p0 += h * Wout[cb + i2];
                p1 += h * Wout[H + cb + i2];
                p2 += h * Wout[2 * H + cb + i2];
            }
            #pragma unroll
            for (int off = 1; off < 16; off <<= 1) {
                p0 += __shfl_xor(p0, off);
                p1 += __shfl_xor(p1, off);
                p2 += __shfl_xor(p2, off);
            }
            if ((t & 15) == 0) {
                out[(size_t)row * 3 + 0] = p0 + bout[0];
                out[(size_t)row * 3 + 1] = p1 + bout[1];
                out[(size_t)row * 3 + 2] = p2 + bout[2];
            }
        }
    }
    if (!do_out) {
        #pragma unroll
        for (int off = 1; off < 64; off <<= 1)
            rmax = fmaxf(rmax, __shfl_xor(rmax, off));
        if ((t & 63) == 0) atomicMax(&gmaxb[li + 1], __float_as_int(rmax));
    }
}

extern "C" void kernel_launch(void* const* d_in, const int* in_sizes, int n_in,
                              void* d_out, int out_size, void* d_ws, size_t ws_size,
                              hipStream_t stream) {
    const float* x     = (const float*)d_in[0];
    const int*   erow  = (const int*)  d_in[1];
    const int*   ecol  = (const int*)  d_in[2];
    const float* ew    = (const float*)d_in[3];
    const float* Win   = (const float*)d_in[4];
    const float* bin   = (const float*)d_in[5];
    const float* Wout  = (const float*)d_in[6];
    const float* bout  = (const float*)d_in[7];
    const float* Wconv = (const float*)d_in[8];
    float* out = (float*)d_out;

    char* ws = (char*)d_ws;
    const size_t NHb = (size_t)N_NODES * H * sizeof(unsigned short);  // 10,240,000
    const size_t NH8 = (size_t)N_NODES * H;                           //  5,120,000
    unsigned short* x0bf = (unsigned short*)(ws);
    unsigned short* hbf  = (unsigned short*)(ws + NHb);     // bf16 residual, in-place
    unsigned char*  hf8A = (unsigned char*)(ws + 2 * NHb);
    unsigned char*  hf8B = (unsigned char*)(ws + 2 * NHb + NH8);
    char* p = ws + 2 * NHb + 2 * NH8;
    unsigned short* Wtbf = (unsigned short*)p;  p += 8 * H * H * 2;   // 262,144
    int* cnt   = (int*)p;                       // N ints
    int* gmaxb = (int*)(p + 160000);            // 16 ints in cnt's pad
    p += 160256;
    unsigned int* bucket = (unsigned int*)p;    // N * CAP * 4 = 15,360,000 B

    // zero counters + gmax slots, then one mega-dispatch
    hipMemsetAsync(cnt, 0, 160256, stream);
    k_setup<<<SB_SCAT + SB_WPRE + SB_XIN, 256, 0, stream>>>(
        erow, ecol, ew, cnt, bucket, Wconv, Wtbf, x, Win, bin, x0bf, gmaxb);

    // layer 0: bf16 gather from x0; writes hbf + fp8 replica (hf8A) + gmax[1]
    k_layer0<<<N_NODES / 32, 256, 0, stream>>>(
        cnt, bucket, x0bf, Wtbf, hbf, hf8A, gmaxb);

    // layers 1..7: fp8 gather; replica ping-pongs (layer l reads buf[(l-1)&1])
    for (int l = 1; l < NLAYERS; l++) {
        const unsigned char* f8in  = ((l - 1) & 1) ? hf8B : hf8A;
        unsigned char*       f8out = ((l - 1) & 1) ? hf8A : hf8B;
        k_layerf8<<<N_NODES / 32, 256, 0, stream>>>(
            cnt, bucket, f8in, f8out, hbf, x0bf,
            Wtbf + (size_t)l * H * H, gmaxb, l, Wout, bout, out,
            (l == NLAYERS - 1) ? 1 : 0);
    }
}

// Round 9
// 543.831 us; speedup vs baseline: 1.6591x; 1.6421x over previous
//
#include <hip/hip_runtime.h>
#include <hip/hip_bf16.h>
#include <math.h>

#define N_NODES 40000
#define NE      640000
#define FIN     33
#define H       128
#define COUT    3
#define NLAYERS 8
#define ALPHA   0.1f
#define THETA   0.5f
#define CAP     96             // max bucket capacity; deg ~ Poisson(16), P(>96) ~ 1e-40
#define HEADROOM 16.0f         // fp8 scale headroom: covers <16x single-layer growth

// setup mega-kernel block ranges (scatter FIRST — longest per-block branch)
#define SB_SCAT 625            // scatter: 625 blocks * 256 thr * 4 edges = 640000
#define SB_WPRE 512            // wprep:   512 blocks * 256 = 131072 elements
#define SB_XIN  2500           // xin:     2500 blocks * 16 nodes = 40000

typedef __bf16 bf16x8 __attribute__((ext_vector_type(8)));
typedef float  f32x4  __attribute__((ext_vector_type(4)));
typedef float  f32x2  __attribute__((ext_vector_type(2)));

__device__ inline unsigned short f2bf(float f) {
    __hip_bfloat16 b = __float2bfloat16(f);
    return *(unsigned short*)&b;
}
__device__ inline float bf2f(unsigned short u) {
    __hip_bfloat16 b = *(__hip_bfloat16*)&u;
    return __bfloat162float(b);
}

// ---- setup mega-kernel: [scatter | wprep(W-fold) | xin] by block range ----
// R1-proven 32-VGPR form. xin reduces a block max of x0 into gmaxb[0]:
// wave shuffle-reduce -> 4-slot LDS -> ONE atomic per block (contention-free).
__global__ __launch_bounds__(256) void k_setup(
        const int* __restrict__ row, const int* __restrict__ col,
        const float* __restrict__ w, int* __restrict__ cnt,
        unsigned int* __restrict__ bucket,
        const float* __restrict__ Wconv, unsigned short* __restrict__ Wtbf,
        const float* __restrict__ x, const float* __restrict__ Win,
        const float* __restrict__ bin,
        unsigned short* __restrict__ x0bf, int* __restrict__ gmaxb) {
    __shared__ float sW[H * FIN];      // used by xin branch only (16.9 KB)
    __shared__ float sx[16][FIN];
    __shared__ float swm[4];
    int b = blockIdx.x, t = threadIdx.x;

    if (b < SB_SCAT) {
        // bucket scatter: 4 independent chains/thread; record = [bf16 w | col]
        int e0 = (b * 256 + t) * 4;
        int r[4], pos[4];
        unsigned int rec[4];
        #pragma unroll
        for (int i = 0; i < 4; i++) {
            int e = e0 + i;
            r[i] = row[e];
            unsigned int wb = f2bf((1.0f - ALPHA) * w[e]);
            rec[i] = (wb << 16) | (unsigned int)col[e];
        }
        #pragma unroll
        for (int i = 0; i < 4; i++) pos[i] = atomicAdd(&cnt[r[i]], 1);
        #pragma unroll
        for (int i = 0; i < 4; i++) bucket[(size_t)r[i] * CAP + pos[i]] = rec[i];
        return;
    }
    if (b < SB_SCAT + SB_WPRE) {
        // W' = (1-beta)*I + beta*W, transposed to [l][j][k], bf16.
        int idx = (b - SB_SCAT) * 256 + t;        // = l*16384 + k*128 + j
        int l = idx >> 14;
        int rem = idx & 16383;
        int k = rem >> 7, j = rem & 127;
        float beta = logf(THETA / (float)(l + 1) + 1.0f);
        float v = beta * Wconv[idx];
        if (j == k) v += 1.0f - beta;
        Wtbf[l * 16384 + j * 128 + k] = f2bf(v);
        return;
    }
    {
        // x0 = relu(x @ W_in^T + b_in) -> bf16; block max -> gmaxb[0]
        int n0 = (b - SB_SCAT - SB_WPRE) * 16;
        for (int i = t; i < H * FIN; i += 256) sW[i] = Win[i];
        for (int i = t; i < 16 * FIN; i += 256)
            sx[i / FIN][i % FIN] = x[(size_t)(n0 + i / FIN) * FIN + (i % FIN)];
        __syncthreads();
        int f = t % H;
        int l0 = t / H;
        float bv = bin[f];
        float tmax = 0.f;
        for (int lo = l0; lo < 16; lo += 2) {
            float acc = bv;
            #pragma unroll
            for (int k = 0; k < FIN; k++) acc += sx[lo][k] * sW[f * FIN + k];
            acc = fmaxf(acc, 0.f);
            tmax = fmaxf(tmax, acc);
            x0bf[(size_t)(n0 + lo) * H + f] = f2bf(acc);
        }
        #pragma unroll
        for (int off = 1; off < 64; off <<= 1)
            tmax = fmaxf(tmax, __shfl_xor(tmax, off));
        if ((t & 63) == 0) swm[t >> 6] = tmax;
        __syncthreads();
        if (t == 0) {
            float m = fmaxf(fmaxf(swm[0], swm[1]), fmaxf(swm[2], swm[3]));
            atomicMax(&gmaxb[0], __float_as_int(m));
        }
    }
}

// ---- layer 0: bf16 gather from x0 (R1-proven phase 1) -----------------
// epilogue writes hbf (bf16 residual) + fp8 replica (scale 448/(16*gmax[0]))
// + block max of h_0 into gmaxb[1] (one atomic per block).
__global__ __launch_bounds__(256) void k_layer0(
        const int* __restrict__ cnt, const unsigned int* __restrict__ bucket,
        const unsigned short* __restrict__ x0bf,
        const unsigned short* __restrict__ Wt,
        unsigned short* __restrict__ hbf,
        unsigned char* __restrict__ f8out, int* __restrict__ gmaxb) {
    __shared__ __align__(16) char smem[16896];   // bf16 xx[32][136] / f32 acc[32][132]
    __shared__ float swm[4];

    int t = threadIdx.x;
    int wv = t >> 6, lane = t & 63;
    int rbase = blockIdx.x * 32;
    float g0 = __int_as_float(gmaxb[0]);          // load scale once at entry
    float Q = g0 > 0.f ? 448.f / (HEADROOM * g0) : 0.f;

    // ---------------- phase 1: bf16 spmm into LDS ----------------
    {
        int slot = lane >> 4;              // 0..3: edge within a group of 4
        int fid  = lane & 15;              // feature block: features fid*8..+7
        for (int i = 0; i < 8; i++) {
            int rloc = wv * 8 + i;
            int row  = rbase + rloc;
            int deg  = cnt[row];
            const unsigned int* ep = bucket + (size_t)row * CAP;
            float acc[8] = {0,0,0,0,0,0,0,0};

            for (int e = 0; e < deg; e += 16) {
                unsigned int u[4];
                uint4 q[4];
                #pragma unroll
                for (int k = 0; k < 4; k++) {
                    int ei = e + k * 4 + slot;           // < CAP always
                    unsigned int uu = ep[ei];
                    u[k] = (ei < deg) ? uu : 0u;
                }
                #pragma unroll
                for (int k = 0; k < 4; k++)
                    q[k] = *(const uint4*)(x0bf + (size_t)(u[k] & 0xffffu) * H + fid * 8);
                #pragma unroll
                for (int k = 0; k < 4; k++) {
                    float w = bf2f((unsigned short)(u[k] >> 16));
                    acc[0] += w * bf2f((unsigned short)(q[k].x & 0xffffu));
                    acc[1] += w * bf2f((unsigned short)(q[k].x >> 16));
                    acc[2] += w * bf2f((unsigned short)(q[k].y & 0xffffu));
                    acc[3] += w * bf2f((unsigned short)(q[k].y >> 16));
                    acc[4] += w * bf2f((unsigned short)(q[k].z & 0xffffu));
                    acc[5] += w * bf2f((unsigned short)(q[k].z >> 16));
                    acc[6] += w * bf2f((unsigned short)(q[k].w & 0xffffu));
                    acc[7] += w * bf2f((unsigned short)(q[k].w >> 16));
                }
            }
            #pragma unroll
            for (int j = 0; j < 8; j++) {
                acc[j] += __shfl_xor(acc[j], 16);
                acc[j] += __shfl_xor(acc[j], 32);
            }
            if (slot == 0) {               // lanes 0..15 hold the full row
                uint4 xq = *(const uint4*)(x0bf + (size_t)row * H + fid * 8);
                float o0 = acc[0] + ALPHA * bf2f((unsigned short)(xq.x & 0xffffu));
                float o1 = acc[1] + ALPHA * bf2f((unsigned short)(xq.x >> 16));
                float o2 = acc[2] + ALPHA * bf2f((unsigned short)(xq.y & 0xffffu));
                float o3 = acc[3] + ALPHA * bf2f((unsigned short)(xq.y >> 16));
                float o4 = acc[4] + ALPHA * bf2f((unsigned short)(xq.z & 0xffffu));
                float o5 = acc[5] + ALPHA * bf2f((unsigned short)(xq.z >> 16));
                float o6 = acc[6] + ALPHA * bf2f((unsigned short)(xq.w & 0xffffu));
                float o7 = acc[7] + ALPHA * bf2f((unsigned short)(xq.w >> 16));
                uint4 r;
                r.x = (unsigned int)f2bf(o0) | ((unsigned int)f2bf(o1) << 16);
                r.y = (unsigned int)f2bf(o2) | ((unsigned int)f2bf(o3) << 16);
                r.z = (unsigned int)f2bf(o4) | ((unsigned int)f2bf(o5) << 16);
                r.w = (unsigned int)f2bf(o6) | ((unsigned int)f2bf(o7) << 16);
                *(uint4*)(smem + (size_t)rloc * 272 + fid * 16) = r;
            }
        }
    }
    __syncthreads();

    // ---------------- phase 2: MFMA GEMM from LDS ----------------
    int quad = lane >> 4, l16 = lane & 15;
    int rh = (wv >> 1) * 16;
    int ch = (wv & 1) * 64;
    f32x4 acc2[4];
    #pragma unroll
    for (int j = 0; j < 4; j++) acc2[j] = (f32x4){0.f, 0.f, 0.f, 0.f};
    #pragma unroll
    for (int k0 = 0; k0 < 4; k0++) {
        bf16x8 av = *(const bf16x8*)(smem + (size_t)(rh + l16) * 272 + k0 * 64 + quad * 16);
        #pragma unroll
        for (int j = 0; j < 4; j++) {
            bf16x8 bv = *(const bf16x8*)(Wt + (size_t)(ch + j * 16 + l16) * H + k0 * 32 + quad * 8);
            acc2[j] = __builtin_amdgcn_mfma_f32_16x16x32_bf16(av, bv, acc2[j], 0, 0, 0);
        }
    }
    __syncthreads();

    // ---------------- phase 3a: acc -> LDS fp32 ----------------
    float* facc = (float*)smem;
    #pragma unroll
    for (int j = 0; j < 4; j++) {
        #pragma unroll
        for (int r = 0; r < 4; r++)
            facc[(rh + quad * 4 + r) * 132 + ch + j * 16 + l16] = acc2[j][r];
    }
    __syncthreads();

    // ---------------- phase 3b: epilogue: residual + fp8 quant ----------
    int cb = (t & 15) * 8;
    float rmax = 0.f;
    #pragma unroll
    for (int p = 0; p < 2; p++) {
        int rloc = p * 16 + (t >> 4);
        int row  = rbase + rloc;
        const float* fr = facc + rloc * 132 + cb;
        f32x4 a0 = *(const f32x4*)fr;
        f32x4 a1 = *(const f32x4*)(fr + 4);
        uint4 hq = *(const uint4*)(x0bf + (size_t)row * H + cb);
        float hv[8];
        hv[0] = bf2f((unsigned short)(hq.x & 0xffffu)) + fmaxf(a0[0], 0.f);
        hv[1] = bf2f((unsigned short)(hq.x >> 16))     + fmaxf(a0[1], 0.f);
        hv[2] = bf2f((unsigned short)(hq.y & 0xffffu)) + fmaxf(a0[2], 0.f);
        hv[3] = bf2f((unsigned short)(hq.y >> 16))     + fmaxf(a0[3], 0.f);
        hv[4] = bf2f((unsigned short)(hq.z & 0xffffu)) + fmaxf(a1[0], 0.f);
        hv[5] = bf2f((unsigned short)(hq.z >> 16))     + fmaxf(a1[1], 0.f);
        hv[6] = bf2f((unsigned short)(hq.w & 0xffffu)) + fmaxf(a1[2], 0.f);
        hv[7] = bf2f((unsigned short)(hq.w >> 16))     + fmaxf(a1[3], 0.f);

        uint4 rr;
        rr.x = (unsigned int)f2bf(hv[0]) | ((unsigned int)f2bf(hv[1]) << 16);
        rr.y = (unsigned int)f2bf(hv[2]) | ((unsigned int)f2bf(hv[3]) << 16);
        rr.z = (unsigned int)f2bf(hv[4]) | ((unsigned int)f2bf(hv[5]) << 16);
        rr.w = (unsigned int)f2bf(hv[6]) | ((unsigned int)f2bf(hv[7]) << 16);
        *(uint4*)(hbf + (size_t)row * H + cb) = rr;

        int d0 = __builtin_amdgcn_cvt_pk_fp8_f32(hv[0] * Q, hv[1] * Q, 0, false);
        d0     = __builtin_amdgcn_cvt_pk_fp8_f32(hv[2] * Q, hv[3] * Q, d0, true);
        int d1 = __builtin_amdgcn_cvt_pk_fp8_f32(hv[4] * Q, hv[5] * Q, 0, false);
        d1     = __builtin_amdgcn_cvt_pk_fp8_f32(hv[6] * Q, hv[7] * Q, d1, true);
        uint2 f8v; f8v.x = (unsigned int)d0; f8v.y = (unsigned int)d1;
        *(uint2*)(f8out + (size_t)row * H + cb) = f8v;

        #pragma unroll
        for (int j = 0; j < 8; j++) rmax = fmaxf(rmax, hv[j]);
    }
    #pragma unroll
    for (int off = 1; off < 64; off <<= 1)
        rmax = fmaxf(rmax, __shfl_xor(rmax, off));
    if ((t & 63) == 0) swm[t >> 6] = rmax;
    __syncthreads();
    if (t == 0) {
        float m = fmaxf(fmaxf(swm[0], swm[1]), fmaxf(swm[2], swm[3]));
        atomicMax(&gmaxb[1], __float_as_int(m));
    }
}

// ---- layers 1..7: fp8 gather (2 cachelines/edge, no scale traffic) -----
// Dequant: ONE uniform multiply (16*gmax[li-1]/448) folded at reduce end.
// Epilogue: residual bf16 in place; quant h_li with 448/(16*gmax[li]);
// block max -> gmaxb[li+1] (one atomic per block). Last layer: out-proj.
__global__ __launch_bounds__(256) void k_layerf8(
        const int* __restrict__ cnt, const unsigned int* __restrict__ bucket,
        const unsigned char* __restrict__ f8in,
        unsigned char* __restrict__ f8out,
        unsigned short* __restrict__ hbf,
        const unsigned short* __restrict__ x0bf,
        const unsigned short* __restrict__ Wt,
        int* __restrict__ gmaxb, int li,
        const float* __restrict__ Wout, const float* __restrict__ bout,
        float* __restrict__ out, int do_out) {
    __shared__ __align__(16) char smem[16896];   // bf16 xx[32][136] / f32 acc[32][132]
    __shared__ float swm[4];

    int t = threadIdx.x;
    int wv = t >> 6, lane = t & 63;
    int rbase = blockIdx.x * 32;

    // load both scales ONCE at kernel entry (uniform)
    float gin = __int_as_float(gmaxb[li - 1]);
    float D = gin > 0.f ? (HEADROOM / 448.f) * gin : 0.f;   // dequant, uniform
    float gq = __int_as_float(gmaxb[li]);
    float Q = gq > 0.f ? 448.f / (HEADROOM * gq) : 0.f;     // quant, uniform

    // ---------------- phase 1: fp8 spmm into LDS ----------------
    {
        int slot = lane >> 3;              // 0..7: edge within a group of 8
        int fid  = lane & 7;               // feature block: features fid*16..+15
        for (int i = 0; i < 8; i++) {
            int rloc = wv * 8 + i;
            int row  = rbase + rloc;
            int deg  = cnt[row];
            const unsigned int* ep = bucket + (size_t)row * CAP;
            float acc[16];
            #pragma unroll
            for (int j = 0; j < 16; j++) acc[j] = 0.f;

            for (int e = 0; e < deg; e += 16) {
                unsigned int u[2];
                uint4 q[2];
                #pragma unroll
                for (int k = 0; k < 2; k++) {
                    int ei = e + k * 8 + slot;           // < CAP always
                    unsigned int uu = ep[ei];
                    u[k] = (ei < deg) ? uu : 0u;         // u=0 -> w=0
                }
                #pragma unroll
                for (int k = 0; k < 2; k++)
                    q[k] = *(const uint4*)(f8in + (size_t)(u[k] & 0xffffu) * H + fid * 16);
                #pragma unroll
                for (int k = 0; k < 2; k++) {
                    float w = bf2f((unsigned short)(u[k] >> 16));
                    unsigned int dw[4] = {q[k].x, q[k].y, q[k].z, q[k].w};
                    #pragma unroll
                    for (int d = 0; d < 4; d++) {
                        f32x2 lo = __builtin_amdgcn_cvt_pk_f32_fp8(dw[d], false);
                        f32x2 hi = __builtin_amdgcn_cvt_pk_f32_fp8(dw[d], true);
                        acc[d * 4 + 0] += w * lo.x;
                        acc[d * 4 + 1] += w * lo.y;
                        acc[d * 4 + 2] += w * hi.x;
                        acc[d * 4 + 3] += w * hi.y;
                    }
                }
            }
            #pragma unroll
            for (int j = 0; j < 16; j++) {
                acc[j] += __shfl_xor(acc[j], 8);
                acc[j] += __shfl_xor(acc[j], 16);
                acc[j] += __shfl_xor(acc[j], 32);
            }
            if (slot == 0) {               // lanes 0..7 hold the full row
                uint4 xa = *(const uint4*)(x0bf + (size_t)row * H + fid * 16);
                uint4 xb = *(const uint4*)(x0bf + (size_t)row * H + fid * 16 + 8);
                unsigned int xw[8] = {xa.x, xa.y, xa.z, xa.w, xb.x, xb.y, xb.z, xb.w};
                uint4 r0, r1;
                unsigned int rr[8];
                #pragma unroll
                for (int p = 0; p < 8; p++) {
                    float o0 = acc[p * 2 + 0] * D + ALPHA * bf2f((unsigned short)(xw[p] & 0xffffu));
                    float o1 = acc[p * 2 + 1] * D + ALPHA * bf2f((unsigned short)(xw[p] >> 16));
                    rr[p] = (unsigned int)f2bf(o0) | ((unsigned int)f2bf(o1) << 16);
                }
                r0.x = rr[0]; r0.y = rr[1]; r0.z = rr[2]; r0.w = rr[3];
                r1.x = rr[4]; r1.y = rr[5]; r1.z = rr[6]; r1.w = rr[7];
                *(uint4*)(smem + (size_t)rloc * 272 + fid * 32) = r0;
                *(uint4*)(smem + (size_t)rloc * 272 + fid * 32 + 16) = r1;
            }
        }
    }
    __syncthreads();

    // ---------------- phase 2: MFMA GEMM from LDS ----------------
    int quad = lane >> 4, l16 = lane & 15;
    int rh = (wv >> 1) * 16;
    int ch = (wv & 1) * 64;
    f32x4 acc2[4];
    #pragma unroll
    for (int j = 0; j < 4; j++) acc2[j] = (f32x4){0.f, 0.f, 0.f, 0.f};
    #pragma unroll
    for (int k0 = 0; k0 < 4; k0++) {
        bf16x8 av = *(const bf16x8*)(smem + (size_t)(rh + l16) * 272 + k0 * 64 + quad * 16);
        #pragma unroll
        for (int j = 0; j < 4; j++) {
            bf16x8 bv = *(const bf16x8*)(Wt + (size_t)(ch + j * 16 + l16) * H + k0 * 32 + quad * 8);
            acc2[j] = __builtin_amdgcn_mfma_f32_16x16x32_bf16(av, bv, acc2[j], 0, 0, 0);
        }
    }
    __syncthreads();

    // ---------------- phase 3a: acc -> LDS fp32 ----------------
    float* facc = (float*)smem;
    #pragma unroll
    for (int j = 0; j < 4; j++) {
        #pragma unroll
        for (int r = 0; r < 4; r++)
            facc[(rh + quad * 4 + r) * 132 + ch + j * 16 + l16] = acc2[j][r];
    }
    __syncthreads();

    // ---------------- phase 3b: coalesced epilogue ----------------
    int cb = (t & 15) * 8;
    float rmax = 0.f;
    #pragma unroll
    for (int p = 0; p < 2; p++) {
        int rloc = p * 16 + (t >> 4);
        int row  = rbase + rloc;
        const float* fr = facc + rloc * 132 + cb;
        f32x4 a0 = *(const f32x4*)fr;
        f32x4 a1 = *(const f32x4*)(fr + 4);
        uint4 hq = *(const uint4*)(hbf + (size_t)row * H + cb);
        float hv[8];
        hv[0] = bf2f((unsigned short)(hq.x & 0xffffu)) + fmaxf(a0[0], 0.f);
        hv[1] = bf2f((unsigned short)(hq.x >> 16))     + fmaxf(a0[1], 0.f);
        hv[2] = bf2f((unsigned short)(hq.y & 0xffffu)) + fmaxf(a0[2], 0.f);
        hv[3] = bf2f((unsigned short)(hq.y >> 16))     + fmaxf(a0[3], 0.f);
        hv[4] = bf2f((unsigned short)(hq.z & 0xffffu)) + fmaxf(a1[0], 0.f);
        hv[5] = bf2f((unsigned short)(hq.z >> 16))     + fmaxf(a1[1], 0.f);
        hv[6] = bf2f((unsigned short)(hq.w & 0xffffu)) + fmaxf(a1[2], 0.f);
        hv[7] = bf2f((unsigned short)(hq.w >> 16))     + fmaxf(a1[3], 0.f);

        if (!do_out) {
            uint4 rr;
            rr.x = (unsigned int)f2bf(hv[0]) | ((unsigned int)f2bf(hv[1]) << 16);
            rr.y = (unsigned int)f2bf(hv[2]) | ((unsigned int)f2bf(hv[3]) << 16);
            rr.z = (unsigned int)f2bf(hv[4]) | ((unsigned int)f2bf(hv[5]) << 16);
            rr.w = (unsigned int)f2bf(hv[6]) | ((unsigned int)f2bf(hv[7]) << 16);
            *(uint4*)(hbf + (size_t)row * H + cb) = rr;
            int d0 = __builtin_amdgcn_cvt_pk_fp8_f32(hv[0] * Q, hv[1] * Q, 0, false);
            d0     = __builtin_amdgcn_cvt_pk_fp8_f32(hv[2] * Q, hv[3] * Q, d0, true);
            int d1 = __builtin_amdgcn_cvt_pk_fp8_f32(hv[4] * Q, hv[5] * Q, 0, false);
            d1     = __builtin_amdgcn_cvt_pk_fp8_f32(hv[6] * Q, hv[7] * Q, d1, true);
            uint2 f8v; f8v.x = (unsigned int)d0; f8v.y = (unsigned int)d1;
            *(uint2*)(f8out + (size_t)row * H + cb) = f8v;
            #pragma unroll
            for (int j = 0; j < 8; j++) rmax = fmaxf(rmax, hv[j]);
        } else {
            float p0 = 0.f, p1 = 0.f, p2 = 0.f;
            #pragma unroll
            for (int i2 = 0; i2 < 8; i2++) {
                float h = hv[i2];
                p0 += h * Wout[cb + i2];
                p1 += h * Wout[H + cb + i2];
                p2 += h * Wout[2 * H + cb + i2];
            }
            #pragma unroll
            for (int off = 1; off < 16; off <<= 1) {
                p0 += __shfl_xor(p0, off);
                p1 += __shfl_xor(p1, off);
                p2 += __shfl_xor(p2, off);
            }
            if ((t & 15) == 0) {
                out[(size_t)row * 3 + 0] = p0 + bout[0];
                out[(size_t)row * 3 + 1] = p1 + bout[1];
                out[(size_t)row * 3 + 2] = p2 + bout[2];
            }
        }
    }
    if (!do_out) {
        #pragma unroll
        for (int off = 1; off < 64; off <<= 1)
            rmax = fmaxf(rmax, __shfl_xor(rmax, off));
        if ((t & 63) == 0) swm[t >> 6] = rmax;
        __syncthreads();
        if (t == 0) {
            float m = fmaxf(fmaxf(swm[0], swm[1]), fmaxf(swm[2], swm[3]));
            atomicMax(&gmaxb[li + 1], __float_as_int(m));
        }
    }
}

extern "C" void kernel_launch(void* const* d_in, const int* in_sizes, int n_in,
                              void* d_out, int out_size, void* d_ws, size_t ws_size,
                              hipStream_t stream) {
    const float* x     = (const float*)d_in[0];
    const int*   erow  = (const int*)  d_in[1];
    const int*   ecol  = (const int*)  d_in[2];
    const float* ew    = (const float*)d_in[3];
    const float* Win   = (const float*)d_in[4];
    const float* bin   = (const float*)d_in[5];
    const float* Wout  = (const float*)d_in[6];
    const float* bout  = (const float*)d_in[7];
    const float* Wconv = (const float*)d_in[8];
    float* out = (float*)d_out;

    char* ws = (char*)d_ws;
    const size_t NHb = (size_t)N_NODES * H * sizeof(unsigned short);  // 10,240,000
    const size_t NH8 = (size_t)N_NODES * H;                           //  5,120,000
    unsigned short* x0bf = (unsigned short*)(ws);
    unsigned short* hbf  = (unsigned short*)(ws + NHb);     // bf16 residual, in-place
    unsigned char*  hf8A = (unsigned char*)(ws + 2 * NHb);
    unsigned char*  hf8B = (unsigned char*)(ws + 2 * NHb + NH8);
    char* p = ws + 2 * NHb + 2 * NH8;
    unsigned short* Wtbf = (unsigned short*)p;  p += 8 * H * H * 2;   // 262,144
    int* cnt   = (int*)p;                       // N ints
    int* gmaxb = (int*)(p + 160000);            // 16 ints in cnt's pad
    p += 160256;
    unsigned int* bucket = (unsigned int*)p;    // N * CAP * 4 = 15,360,000 B

    // zero counters + gmax slots, then one mega-dispatch
    hipMemsetAsync(cnt, 0, 160256, stream);
    k_setup<<<SB_SCAT + SB_WPRE + SB_XIN, 256, 0, stream>>>(
        erow, ecol, ew, cnt, bucket, Wconv, Wtbf, x, Win, bin, x0bf, gmaxb);

    // layer 0: bf16 gather from x0; writes hbf + fp8 replica (hf8A) + gmax[1]
    k_layer0<<<N_NODES / 32, 256, 0, stream>>>(
        cnt, bucket, x0bf, Wtbf, hbf, hf8A, gmaxb);

    // layers 1..7: fp8 gather; replica ping-pongs (layer l reads buf[(l-1)&1])
    for (int l = 1; l < NLAYERS; l++) {
        const unsigned char* f8in  = ((l - 1) & 1) ? hf8B : hf8A;
        unsigned char*       f8out = ((l - 1) & 1) ? hf8A : hf8B;
        k_layerf8<<<N_NODES / 32, 256, 0, stream>>>(
            cnt, bucket, f8in, f8out, hbf, x0bf,
            Wtbf + (size_t)l * H * H, gmaxb, l, Wout, bout, out,
            (l == NLAYERS - 1) ? 1 : 0);
    }
}